// Round 1
// baseline (739.243 us; speedup 1.0000x reference)
//
#include <hip/hip_runtime.h>
#include <math.h>

#define NT 256
#define NBATCH 512
#define NPTS 2000
#define NSEL 1000
#define NOUT 50

__device__ __forceinline__ float sl1(float x){ float d = fabsf(x); return d < 1.f ? 0.5f*d*d : d - 0.5f; }
__device__ __forceinline__ float gelu_(float x){ return 0.5f*x*(1.f + erff(x*0.70710678118654752440f)); }

__device__ __forceinline__ unsigned mono(float f){
  unsigned u = __float_as_uint(f);
  return u ^ ((u >> 31) ? 0xFFFFFFFFu : 0x80000000u);
}

__device__ __forceinline__ float blk_sum(float v, float* s, int tid){
  #pragma unroll
  for (int o = 32; o > 0; o >>= 1) v += __shfl_down(v, o);
  __syncthreads();
  if ((tid & 63) == 0) s[tid >> 6] = v;
  __syncthreads();
  return (s[0]+s[1])+(s[2]+s[3]);
}
__device__ __forceinline__ float blk_max(float v, float* s, int tid){
  #pragma unroll
  for (int o = 32; o > 0; o >>= 1) v = fmaxf(v, __shfl_down(v, o));
  __syncthreads();
  if ((tid & 63) == 0) s[tid >> 6] = v;
  __syncthreads();
  return fmaxf(fmaxf(s[0],s[1]), fmaxf(s[2],s[3]));
}
__device__ __forceinline__ unsigned long long blk_min_u64(unsigned long long v, unsigned long long* s, int tid){
  #pragma unroll
  for (int o = 32; o > 0; o >>= 1){ unsigned long long w = __shfl_down(v, o); v = (w < v) ? w : v; }
  __syncthreads();
  if ((tid & 63) == 0) s[tid >> 6] = v;
  __syncthreads();
  unsigned long long a = s[0] < s[1] ? s[0] : s[1];
  unsigned long long b = s[2] < s[3] ? s[2] : s[3];
  return a < b ? a : b;
}

__device__ void bitonic(unsigned long long* buf, int n, int tid){
  for (int k = 2; k <= n; k <<= 1){
    for (int j = k >> 1; j > 0; j >>= 1){
      for (int i = tid; i < n; i += NT){
        int ixj = i ^ j;
        if (ixj > i){
          unsigned long long a = buf[i], c = buf[ixj];
          bool up = (i & k) == 0;
          if ((a > c) == up){ buf[i] = c; buf[ixj] = a; }
        }
      }
      __syncthreads();
    }
  }
}

// LayerNorm (mean/var over 64) + affine + exact gelu, in-register.
__device__ __forceinline__ void ln_gelu(float (&h)[64], const float* __restrict__ g, const float* __restrict__ be){
  float s0=0.f,s1=0.f,s2=0.f,s3=0.f;
  #pragma unroll
  for (int j=0;j<16;j++){ s0+=h[j]; s1+=h[j+16]; s2+=h[j+32]; s3+=h[j+48]; }
  float m = ((s0+s1)+(s2+s3)) * 0.015625f;
  s0=s1=s2=s3=0.f;
  #pragma unroll
  for (int j=0;j<16;j++){
    float a=h[j]-m, b=h[j+16]-m, c=h[j+32]-m, d=h[j+48]-m;
    s0+=a*a; s1+=b*b; s2+=c*c; s3+=d*d;
  }
  float v = ((s0+s1)+(s2+s3)) * 0.015625f;
  float r = 1.0f / __fsqrt_rn(v + 1e-5f);
  #pragma unroll
  for (int j=0;j<64;j++){
    float x = (h[j]-m)*r;
    x = x * g[j] + be[j];
    h[j] = gelu_(x);
  }
}

__global__ void init_k(double* acc){
  if (threadIdx.x < 8) acc[threadIdx.x] = 0.0;
}

__global__ __launch_bounds__(NT) void main_k(
    const float* __restrict__ osm, const float* __restrict__ agent, const float* __restrict__ vect,
    const float* __restrict__ endp,
    const float* __restrict__ oxw1, const float* __restrict__ oxb1, const float* __restrict__ oxg1, const float* __restrict__ oxbe1,
    const float* __restrict__ oxw2, const float* __restrict__ oxb2,
    const float* __restrict__ tpw1, const float* __restrict__ tpb1, const float* __restrict__ tpg1, const float* __restrict__ tpbe1,
    const float* __restrict__ tpw2, const float* __restrict__ tpb2, const float* __restrict__ tpg2, const float* __restrict__ tpbe2,
    const float* __restrict__ tpw3, const float* __restrict__ tpb3,
    float* __restrict__ out, double* __restrict__ acc)
{
  const int b = blockIdx.x;
  const int tid = threadIdx.x;

  __shared__ unsigned long long sbuf[2048];
  __shared__ float ptsx[NSEL], ptsy[NSEL], tgx[NSEL], tgy[NSEL], pol[NSEL];
  __shared__ float vfs[64], ats[64], bo[64], bt[64];
  __shared__ float red[4];
  __shared__ unsigned long long redk[4];

  if (tid < 64){ vfs[tid] = vect[b*64 + tid]; ats[tid] = agent[b*64 + tid]; }

  // ---- phase 1: stable sort of all 2000 points by dist-to-origin ----
  for (int i = tid; i < 2048; i += NT){
    unsigned long long key = 0xFFFFFFFFFFFFFFFFULL;
    if (i < NPTS){
      const float px = osm[((size_t)b*NPTS + i)*4 + 0];
      const float py = osm[((size_t)b*NPTS + i)*4 + 1];
      const float d = __fsqrt_rn(px*px + py*py);
      key = ((unsigned long long)mono(d) << 32) | (unsigned)i;
    }
    sbuf[i] = key;
  }
  __syncthreads();
  bitonic(sbuf, 2048, tid);

  // gather selected pts (in reference order)
  for (int i = tid; i < NSEL; i += NT){
    const int p = (int)(sbuf[i] & 0xFFFFFFFFu);
    ptsx[i] = osm[((size_t)b*NPTS + p)*4 + 0];
    ptsy[i] = osm[((size_t)b*NPTS + p)*4 + 1];
  }

  // per-batch constant parts of the first-layer matmuls
  if (tid < 64){
    float s1 = oxb1[tid], s2 = tpb1[tid];
    for (int k = 0; k < 64; k++){
      s1 += vfs[k]*oxw1[k*64 + tid];
      s2 += vfs[k]*tpw1[k*64 + tid];
    }
    for (int k = 0; k < 64; k++){
      s1 += ats[k]*oxw1[(64+k)*64 + tid];
      s2 += ats[k]*tpw1[(64+k)*64 + tid];
    }
    bo[tid] = s1; bt[tid] = s2;
  }
  __syncthreads();

  const float ex = endp[b*2 + 0], ey = endp[b*2 + 1];

  // ---- phase 2: per-point MLP ----
  float loff = 0.f;
  unsigned long long dkey = 0xFFFFFFFFFFFFFFFFULL;
  for (int i = tid; i < NSEL; i += NT){
    const float px = ptsx[i], py = ptsy[i];
    float h[64];
    #pragma unroll
    for (int j = 0; j < 64; j++) h[j] = bo[j] + px*oxw1[128*64 + j] + py*oxw1[129*64 + j];
    ln_gelu(h, oxg1, oxbe1);
    float o0 = oxb2[0], o1 = oxb2[1];
    #pragma unroll
    for (int j = 0; j < 64; j++){ o0 += h[j]*oxw2[2*j]; o1 += h[j]*oxw2[2*j+1]; }
    const float tx = px + o0, ty = py + o1;

    #pragma unroll
    for (int j = 0; j < 64; j++) h[j] = bt[j] + tx*tpw1[128*64 + j] + ty*tpw1[129*64 + j];
    ln_gelu(h, tpg1, tpbe1);

    float a2[64];
    #pragma unroll
    for (int j = 0; j < 64; j++) a2[j] = tpb2[j];
    #pragma unroll
    for (int k = 0; k < 64; k++){
      const float hk = h[k];
      #pragma unroll
      for (int j = 0; j < 64; j++) a2[j] += hk * tpw2[k*64 + j];
    }
    ln_gelu(a2, tpg2, tpbe2);

    float t0 = tpb3[0], t1 = tpb3[1];
    #pragma unroll
    for (int j = 0; j < 64; j++){ t0 += a2[j]*tpw3[2*j]; t1 += a2[j]*tpw3[2*j+1]; }

    tgx[i] = t0; tgy[i] = t1;
    loff += sl1(t0 - ex) + sl1(t1 - ey);

    // argmax of softmax(-d/TEMP) == max of x=-d/0.01, tie -> smallest i
    const float ddx = px - ex, ddy = py - ey;
    const float dd = __fsqrt_rn(ddx*ddx + ddy*ddy);
    const float xv = (0.0f - dd) / 0.01f;
    const unsigned long long k2 = ((unsigned long long)(~mono(xv)) << 32) | (unsigned)i;
    dkey = (k2 < dkey) ? k2 : dkey;
  }

  const float loffT = blk_sum(loff, red, tid);
  const unsigned long long dmin = blk_min_u64(dkey, redk, tid);

  // ---- phase 3: mean / var (ddof=1) of targets ----
  float sx = 0.f, sy = 0.f;
  for (int i = tid; i < NSEL; i += NT){ sx += tgx[i]; sy += tgy[i]; }
  const float mx = blk_sum(sx, red, tid) * (1.0f/NSEL);
  const float my = blk_sum(sy, red, tid) * (1.0f/NSEL);
  float qx = 0.f, qy = 0.f;
  for (int i = tid; i < NSEL; i += NT){
    const float dx = tgx[i]-mx, dy = tgy[i]-my;
    qx += dx*dx; qy += dy*dy;
  }
  const float vx = blk_sum(qx, red, tid) * (1.0f/(NSEL-1));
  const float vy = blk_sum(qy, red, tid) * (1.0f/(NSEL-1));

  const float TWO_PI = 6.2831853071795864769f;
  const float rdenx = 1.0f / __fsqrt_rn(TWO_PI*vx + 1e-6f);
  const float rdeny = 1.0f / __fsqrt_rn(TWO_PI*vy + 1e-6f);

  // ---- phase 4: policy ----
  float pmaxl = -INFINITY;
  for (int i = tid; i < NSEL; i += NT){
    const float dx = tgx[i]-mx, dy = tgy[i]-my;
    const float pdx = expf((-0.5f*dx*dx)/vx + 1e-6f) * rdenx;
    const float pdy = expf((-0.5f*dy*dy)/vy + 1e-6f) * rdeny;
    const float p = pdx*pdy;
    pol[i] = p;
    pmaxl = fmaxf(pmaxl, p);
  }
  const float pmax = blk_max(pmaxl, red, tid);
  float sel = 0.f;
  for (int i = tid; i < NSEL; i += NT) sel += expf(pol[i] - pmax);
  const float sumexp = blk_sum(sel, red, tid);

  if (tid == 0){
    const float lse = pmax + logf(sumexp);
    const float picked = pol[(int)(dmin & 0xFFFFFFFFu)];
    atomicAdd(&acc[0], (double)(lse - picked));
    atomicAdd(&acc[1], (double)loffT);
  }

  // ---- phase 5: top-50 by policy (stable descending) ----
  for (int i = tid; i < 1024; i += NT){
    unsigned long long key = 0xFFFFFFFFFFFFFFFFULL;
    if (i < NSEL){
      key = ((unsigned long long)(~mono(pol[i])) << 32) | (unsigned)i;
    }
    sbuf[i] = key;
  }
  __syncthreads();
  bitonic(sbuf, 1024, tid);

  float lend = 0.f;
  for (int r = tid; r < NOUT; r += NT){
    const int i = (int)(sbuf[r] & 0xFFFFFFFFu);
    const float t0 = tgx[i], t1 = tgy[i];
    out[2 + ((size_t)b*NOUT + r)*2 + 0] = t0;
    out[2 + ((size_t)b*NOUT + r)*2 + 1] = t1;
    lend += sl1(t0 - ex) + sl1(t1 - ey);
  }
  const float lendT = blk_sum(lend, red, tid);
  if (tid == 0) atomicAdd(&acc[2], (double)lendT);
}

__global__ void fin_k(const double* acc, float* out){
  if (threadIdx.x == 0){
    out[0] = (float)(acc[0] / (double)NBATCH);
    out[1] = (float)(acc[1] / ((double)NBATCH*NSEL*2) + 3.0 * (acc[2] / ((double)NBATCH*NOUT*2)));
  }
}

extern "C" void kernel_launch(void* const* d_in, const int* in_sizes, int n_in,
                              void* d_out, int out_size, void* d_ws, size_t ws_size,
                              hipStream_t stream){
  const float* osm   = (const float*)d_in[0];
  const float* agent = (const float*)d_in[1];
  const float* vect  = (const float*)d_in[2];
  const float* endp  = (const float*)d_in[3];
  // d_in[4] = speed (unused)
  const float* oxw1  = (const float*)d_in[5];
  const float* oxb1  = (const float*)d_in[6];
  const float* oxg1  = (const float*)d_in[7];
  const float* oxbe1 = (const float*)d_in[8];
  const float* oxw2  = (const float*)d_in[9];
  const float* oxb2  = (const float*)d_in[10];
  const float* tpw1  = (const float*)d_in[11];
  const float* tpb1  = (const float*)d_in[12];
  const float* tpg1  = (const float*)d_in[13];
  const float* tpbe1 = (const float*)d_in[14];
  const float* tpw2  = (const float*)d_in[15];
  const float* tpb2  = (const float*)d_in[16];
  const float* tpg2  = (const float*)d_in[17];
  const float* tpbe2 = (const float*)d_in[18];
  const float* tpw3  = (const float*)d_in[19];
  const float* tpb3  = (const float*)d_in[20];
  float* out = (float*)d_out;
  double* acc = (double*)d_ws;

  hipLaunchKernelGGL(init_k, dim3(1), dim3(64), 0, stream, acc);
  hipLaunchKernelGGL(main_k, dim3(NBATCH), dim3(NT), 0, stream,
    osm, agent, vect, endp,
    oxw1, oxb1, oxg1, oxbe1, oxw2, oxb2,
    tpw1, tpb1, tpg1, tpbe1, tpw2, tpb2, tpg2, tpbe2, tpw3, tpb3,
    out, acc);
  hipLaunchKernelGGL(fin_k, dim3(1), dim3(64), 0, stream, acc, out);
}

// Round 2
// 715.977 us; speedup vs baseline: 1.0325x; 1.0325x over previous
//
#include <hip/hip_runtime.h>
#include <math.h>

#define NT 256
#define NBATCH 512
#define NPTS 2000
#define NSEL 1000
#define NOUT 50

__device__ __forceinline__ float sl1(float x){ float d = fabsf(x); return d < 1.f ? 0.5f*d*d : d - 0.5f; }
__device__ __forceinline__ float gelu_(float x){ return 0.5f*x*(1.f + erff(x*0.70710678118654752440f)); }

__device__ __forceinline__ unsigned mono(float f){
  unsigned u = __float_as_uint(f);
  return u ^ ((u >> 31) ? 0xFFFFFFFFu : 0x80000000u);
}

__device__ __forceinline__ float rl(float v, int l){
  return __builtin_bit_cast(float, __builtin_amdgcn_readlane(__builtin_bit_cast(int, v), l));
}

// butterfly sum of two values across the 64-lane wave (all lanes get totals)
__device__ __forceinline__ void wsum2(float& a, float& b){
  #pragma unroll
  for (int s = 1; s < 64; s <<= 1){
    a += __shfl_xor(a, s, 64);
    b += __shfl_xor(b, s, 64);
  }
}

// cooperative LayerNorm over the 64 lanes (one channel per lane) + affine
__device__ __forceinline__ float ln_coop(float x, float g, float be){
  float s = x, q = x*x;
  wsum2(s, q);
  const float m = s * 0.015625f;
  const float v = q * 0.015625f - m*m;
  const float r = 1.0f / __fsqrt_rn(v + 1e-5f);
  return (x - m)*r*g + be;
}

__device__ __forceinline__ float blk_sum(float v, float* s, int tid){
  #pragma unroll
  for (int o = 32; o > 0; o >>= 1) v += __shfl_down(v, o);
  __syncthreads();
  if ((tid & 63) == 0) s[tid >> 6] = v;
  __syncthreads();
  return (s[0]+s[1])+(s[2]+s[3]);
}
__device__ __forceinline__ float blk_max(float v, float* s, int tid){
  #pragma unroll
  for (int o = 32; o > 0; o >>= 1) v = fmaxf(v, __shfl_down(v, o));
  __syncthreads();
  if ((tid & 63) == 0) s[tid >> 6] = v;
  __syncthreads();
  return fmaxf(fmaxf(s[0],s[1]), fmaxf(s[2],s[3]));
}
__device__ __forceinline__ unsigned long long blk_min_u64(unsigned long long v, unsigned long long* s, int tid){
  #pragma unroll
  for (int o = 32; o > 0; o >>= 1){ unsigned long long w = __shfl_down(v, o); v = (w < v) ? w : v; }
  __syncthreads();
  if ((tid & 63) == 0) s[tid >> 6] = v;
  __syncthreads();
  unsigned long long a = s[0] < s[1] ? s[0] : s[1];
  unsigned long long b = s[2] < s[3] ? s[2] : s[3];
  return a < b ? a : b;
}

// bitonic sort, pair-indexed (n/2 work items per stage)
__device__ void bitonic(unsigned long long* buf, int n, int tid){
  for (int k = 2; k <= n; k <<= 1){
    for (int j = k >> 1; j > 0; j >>= 1){
      for (int t = tid; t < (n >> 1); t += NT){
        const int i = ((t & ~(j-1)) << 1) | (t & (j-1));
        const int p = i | j;
        unsigned long long a = buf[i], c = buf[p];
        const bool up = (i & k) == 0;
        if ((a > c) == up){ buf[i] = c; buf[p] = a; }
      }
      __syncthreads();
    }
  }
}

__global__ void init_k(double* acc){
  if (threadIdx.x < 8) acc[threadIdx.x] = 0.0;
}

__global__ __launch_bounds__(NT, 4) void main_k(
    const float* __restrict__ osm, const float* __restrict__ agent, const float* __restrict__ vect,
    const float* __restrict__ endp,
    const float* __restrict__ oxw1, const float* __restrict__ oxb1, const float* __restrict__ oxg1, const float* __restrict__ oxbe1,
    const float* __restrict__ oxw2, const float* __restrict__ oxb2,
    const float* __restrict__ tpw1, const float* __restrict__ tpb1, const float* __restrict__ tpg1, const float* __restrict__ tpbe1,
    const float* __restrict__ tpw2, const float* __restrict__ tpb2, const float* __restrict__ tpg2, const float* __restrict__ tpbe2,
    const float* __restrict__ tpw3, const float* __restrict__ tpb3,
    float* __restrict__ out, double* __restrict__ acc)
{
  const int b = blockIdx.x;
  const int tid = threadIdx.x;
  const int lane = tid & 63;
  const int wv = tid >> 6;

  __shared__ unsigned long long sbuf[2048];
  __shared__ float2 tg[NSEL];
  __shared__ float pol[NSEL];
  __shared__ float vfs[64], ats[64], bo[64], bt[64];
  __shared__ float red[4];
  __shared__ unsigned long long redk[4];
  float2* ptf2 = (float2*)(sbuf + 1024);   // selected points, overlaid on sbuf tail

  // ---- persistent per-lane parameters (channel j = lane) ----
  const float cx_ox = oxw1[128*64 + lane], cy_ox = oxw1[129*64 + lane];
  const float g1o = oxg1[lane], be1o = oxbe1[lane];
  const float w2c0 = oxw2[lane*2 + 0], w2c1 = oxw2[lane*2 + 1];
  const float cx_tp = tpw1[128*64 + lane], cy_tp = tpw1[129*64 + lane];
  const float g1t = tpg1[lane], be1t = tpbe1[lane];
  const float g2t = tpg2[lane], be2t = tpbe2[lane];
  const float b2t = tpb2[lane];
  const float t3a = tpw3[lane*2 + 0], t3b = tpw3[lane*2 + 1];
  float w2c[64];                                   // column `lane` of tpw2
  #pragma unroll
  for (int k = 0; k < 64; k++) w2c[k] = tpw2[k*64 + lane];
  const float oxb2_0 = oxb2[0], oxb2_1 = oxb2[1];
  const float tpb3_0 = tpb3[0], tpb3_1 = tpb3[1];
  const float ex = endp[b*2 + 0], ey = endp[b*2 + 1];

  if (tid < 64){ vfs[tid] = vect[b*64 + tid]; ats[tid] = agent[b*64 + tid]; }

  // ---- phase 1: fill keys (dist to origin, stable by index) ----
  const float2* osm2 = (const float2*)osm;  // view: row i -> osm2[2i] = (x,y)
  for (int i = tid; i < 2048; i += NT){
    unsigned long long key = 0xFFFFFFFFFFFFFFFFULL;
    if (i < NPTS){
      const float2 p = osm2[((size_t)b*NPTS + i)*2];
      const float d = __fsqrt_rn(p.x*p.x + p.y*p.y);
      key = ((unsigned long long)mono(d) << 32) | (unsigned)i;
    }
    sbuf[i] = key;
  }
  __syncthreads();

  // per-batch constant parts of first-layer matmuls (wave0 -> bo, wave1 -> bt)
  if (tid < 64){
    float s = oxb1[tid];
    for (int k = 0; k < 64; k++) s += vfs[k]*oxw1[k*64 + tid] + ats[k]*oxw1[(64+k)*64 + tid];
    bo[tid] = s;
  } else if (tid < 128){
    const int l = tid - 64;
    float s = tpb1[l];
    for (int k = 0; k < 64; k++) s += vfs[k]*tpw1[k*64 + l] + ats[k]*tpw1[(64+k)*64 + l];
    bt[l] = s;
  }

  bitonic(sbuf, 2048, tid);

  // gather selected points (reference order) into ptf2
  for (int i = tid; i < NSEL; i += NT){
    const int p = (int)(sbuf[i] & 0xFFFFFFFFu);
    ptf2[i] = osm2[((size_t)b*NPTS + p)*2];
  }
  __syncthreads();

  const float bo_l = bo[lane], bt_l = bt[lane];

  // ---- target_index: argmax softmax(-d/T) == min over (~mono(-d/T), i) ----
  unsigned long long dkey = 0xFFFFFFFFFFFFFFFFULL;
  for (int i = tid; i < NSEL; i += NT){
    const float2 p = ptf2[i];
    const float ddx = p.x - ex, ddy = p.y - ey;
    const float dd = __fsqrt_rn(ddx*ddx + ddy*ddy);
    const float xv = (0.0f - dd) / 0.01f;
    const unsigned long long k2 = ((unsigned long long)(~mono(xv)) << 32) | (unsigned)i;
    dkey = (k2 < dkey) ? k2 : dkey;
  }

  // ---- phase 2: wave-cooperative MLP, one point per wave-iteration ----
  float loff = 0.f;
  for (int i = wv; i < NSEL; i += 4){
    const float2 p = ptf2[i];
    // ox: layer1 + LN + gelu
    float x = fmaf(p.x, cx_ox, fmaf(p.y, cy_ox, bo_l));
    float g = gelu_(ln_coop(x, g1o, be1o));
    // ox: 64 -> 2
    float u = g * w2c0, v = g * w2c1;
    wsum2(u, v);
    const float tx = p.x + u + oxb2_0, ty = p.y + v + oxb2_1;
    // tp layer1 + LN + gelu
    x = fmaf(tx, cx_tp, fmaf(ty, cy_tp, bt_l));
    g = gelu_(ln_coop(x, g1t, be1t));
    // tp 64x64 matmul: broadcast g via readlane, per-lane column in regs
    float a0 = b2t, a1 = 0.f, a2 = 0.f, a3 = 0.f;
    #pragma unroll
    for (int k = 0; k < 64; k += 4){
      a0 = fmaf(rl(g, k+0), w2c[k+0], a0);
      a1 = fmaf(rl(g, k+1), w2c[k+1], a1);
      a2 = fmaf(rl(g, k+2), w2c[k+2], a2);
      a3 = fmaf(rl(g, k+3), w2c[k+3], a3);
    }
    const float h2 = (a0+a1)+(a2+a3);
    g = gelu_(ln_coop(h2, g2t, be2t));
    // tp 64 -> 2
    u = g * t3a; v = g * t3b;
    wsum2(u, v);
    const float t0 = u + tpb3_0, t1 = v + tpb3_1;
    if (lane == 0){
      tg[i] = make_float2(t0, t1);
      loff += sl1(t0 - ex) + sl1(t1 - ey);
    }
  }
  __syncthreads();

  const float loffT = blk_sum(loff, red, tid);
  const unsigned long long dmin = blk_min_u64(dkey, redk, tid);

  // ---- phase 3: mean / var (ddof=1) of targets ----
  float sx = 0.f, sy = 0.f;
  for (int i = tid; i < NSEL; i += NT){ const float2 t = tg[i]; sx += t.x; sy += t.y; }
  const float mx = blk_sum(sx, red, tid) * (1.0f/NSEL);
  const float my = blk_sum(sy, red, tid) * (1.0f/NSEL);
  float qx = 0.f, qy = 0.f;
  for (int i = tid; i < NSEL; i += NT){
    const float2 t = tg[i];
    const float dx = t.x-mx, dy = t.y-my;
    qx += dx*dx; qy += dy*dy;
  }
  const float vx = blk_sum(qx, red, tid) * (1.0f/(NSEL-1));
  const float vy = blk_sum(qy, red, tid) * (1.0f/(NSEL-1));

  const float TWO_PI = 6.2831853071795864769f;
  const float rdenx = 1.0f / __fsqrt_rn(TWO_PI*vx + 1e-6f);
  const float rdeny = 1.0f / __fsqrt_rn(TWO_PI*vy + 1e-6f);

  // ---- phase 4: policy ----
  float pmaxl = -INFINITY;
  for (int i = tid; i < NSEL; i += NT){
    const float2 t = tg[i];
    const float dx = t.x-mx, dy = t.y-my;
    const float pdx = expf((-0.5f*dx*dx)/vx + 1e-6f) * rdenx;
    const float pdy = expf((-0.5f*dy*dy)/vy + 1e-6f) * rdeny;
    const float p = pdx*pdy;
    pol[i] = p;
    pmaxl = fmaxf(pmaxl, p);
  }
  const float pmax = blk_max(pmaxl, red, tid);
  float sel = 0.f;
  for (int i = tid; i < NSEL; i += NT) sel += expf(pol[i] - pmax);
  const float sumexp = blk_sum(sel, red, tid);

  if (tid == 0){
    const float lse = pmax + logf(sumexp);
    const float picked = pol[(int)(dmin & 0xFFFFFFFFu)];
    atomicAdd(&acc[0], (double)(lse - picked));
    atomicAdd(&acc[1], (double)loffT);
  }

  // ---- phase 5: top-50 by policy (stable descending) ----
  for (int i = tid; i < 1024; i += NT){
    unsigned long long key = 0xFFFFFFFFFFFFFFFFULL;
    if (i < NSEL) key = ((unsigned long long)(~mono(pol[i])) << 32) | (unsigned)i;
    sbuf[i] = key;
  }
  __syncthreads();
  bitonic(sbuf, 1024, tid);

  float lend = 0.f;
  for (int r = tid; r < NOUT; r += NT){
    const int i = (int)(sbuf[r] & 0xFFFFFFFFu);
    const float2 t = tg[i];
    out[2 + ((size_t)b*NOUT + r)*2 + 0] = t.x;
    out[2 + ((size_t)b*NOUT + r)*2 + 1] = t.y;
    lend += sl1(t.x - ex) + sl1(t.y - ey);
  }
  const float lendT = blk_sum(lend, red, tid);
  if (tid == 0) atomicAdd(&acc[2], (double)lendT);
}

__global__ void fin_k(const double* acc, float* out){
  if (threadIdx.x == 0){
    out[0] = (float)(acc[0] / (double)NBATCH);
    out[1] = (float)(acc[1] / ((double)NBATCH*NSEL*2) + 3.0 * (acc[2] / ((double)NBATCH*NOUT*2)));
  }
}

extern "C" void kernel_launch(void* const* d_in, const int* in_sizes, int n_in,
                              void* d_out, int out_size, void* d_ws, size_t ws_size,
                              hipStream_t stream){
  const float* osm   = (const float*)d_in[0];
  const float* agent = (const float*)d_in[1];
  const float* vect  = (const float*)d_in[2];
  const float* endp  = (const float*)d_in[3];
  // d_in[4] = speed (unused)
  const float* oxw1  = (const float*)d_in[5];
  const float* oxb1  = (const float*)d_in[6];
  const float* oxg1  = (const float*)d_in[7];
  const float* oxbe1 = (const float*)d_in[8];
  const float* oxw2  = (const float*)d_in[9];
  const float* oxb2  = (const float*)d_in[10];
  const float* tpw1  = (const float*)d_in[11];
  const float* tpb1  = (const float*)d_in[12];
  const float* tpg1  = (const float*)d_in[13];
  const float* tpbe1 = (const float*)d_in[14];
  const float* tpw2  = (const float*)d_in[15];
  const float* tpb2  = (const float*)d_in[16];
  const float* tpg2  = (const float*)d_in[17];
  const float* tpbe2 = (const float*)d_in[18];
  const float* tpw3  = (const float*)d_in[19];
  const float* tpb3  = (const float*)d_in[20];
  float* out = (float*)d_out;
  double* acc = (double*)d_ws;

  hipLaunchKernelGGL(init_k, dim3(1), dim3(64), 0, stream, acc);
  hipLaunchKernelGGL(main_k, dim3(NBATCH), dim3(NT), 0, stream,
    osm, agent, vect, endp,
    oxw1, oxb1, oxg1, oxbe1, oxw2, oxb2,
    tpw1, tpb1, tpg1, tpbe1, tpw2, tpb2, tpg2, tpbe2, tpw3, tpb3,
    out, acc);
  hipLaunchKernelGGL(fin_k, dim3(1), dim3(64), 0, stream, acc, out);
}

// Round 3
// 255.822 us; speedup vs baseline: 2.8897x; 2.7987x over previous
//
#include <hip/hip_runtime.h>
#include <math.h>

#define NT 256
#define NB 512
#define NP 2000
#define NS 1000
#define NO 50

typedef unsigned int u32;
typedef unsigned long long u64;
typedef unsigned short u16;
typedef unsigned char u8;
typedef __attribute__((ext_vector_type(8))) short short8;
typedef __attribute__((ext_vector_type(4))) float f32x4;

__device__ __forceinline__ float sl1(float x){ float d = fabsf(x); return d < 1.f ? 0.5f*d*d : d - 0.5f; }

__device__ __forceinline__ u32 mono(float f){
  u32 u = __float_as_uint(f);
  return u ^ ((u >> 31) ? 0xFFFFFFFFu : 0x80000000u);
}
// bitwise-exact vs jnp: mul, mul, add, sqrt all RN, no contraction
__device__ __forceinline__ float dist_rn(float x, float y){
  return __fsqrt_rn(__fadd_rn(__fmul_rn(x,x), __fmul_rn(y,y)));
}
__device__ __forceinline__ float rl(float v, int l){
  return __builtin_bit_cast(float, __builtin_amdgcn_readlane(__builtin_bit_cast(int, v), l));
}
__device__ __forceinline__ u16 f2bf(float f){           // RNE f32->bf16
  u32 u = __float_as_uint(f);
  u32 r = (u + 0x7FFFu + ((u >> 16) & 1u)) >> 16;
  return (u16)r;
}
__device__ __forceinline__ float bf2f(u16 h){ return __uint_as_float(((u32)h) << 16); }

// gelu via Abramowitz-Stegun 7.1.26 erf (|eps| <= 1.5e-7), ~16 VALU
__device__ __forceinline__ float gelu_(float x){
  float z = x * 0.70710678118654752440f;
  float az = fabsf(z);
  float t = __frcp_rn(fmaf(0.3275911f, az, 1.0f));
  float p =          fmaf(t, 1.061405429f, -1.453152027f);
  p = fmaf(p, t, 1.421413741f);
  p = fmaf(p, t, -0.284496736f);
  p = fmaf(p, t, 0.254829592f);
  p = p * t;
  float e = __expf(-az*az);
  float er = fmaf(-p, e, 1.0f);
  er = copysignf(er, z);
  float hx = 0.5f * x;
  return fmaf(hx, er, hx);
}
__device__ __forceinline__ float wred(float v){  // full-wave sum
  #pragma unroll
  for (int s = 1; s < 64; s <<= 1) v += __shfl_xor(v, s, 64);
  return v;
}
__device__ __forceinline__ float bsum(float v, float* s, int tid){
  #pragma unroll
  for (int o = 32; o > 0; o >>= 1) v += __shfl_down(v, o, 64);
  __syncthreads();
  if ((tid & 63) == 0) s[tid >> 6] = v;
  __syncthreads();
  return (s[0]+s[1])+(s[2]+s[3]);
}
__device__ __forceinline__ float bmax(float v, float* s, int tid){
  #pragma unroll
  for (int o = 32; o > 0; o >>= 1) v = fmaxf(v, __shfl_down(v, o, 64));
  __syncthreads();
  if ((tid & 63) == 0) s[tid >> 6] = v;
  __syncthreads();
  return fmaxf(fmaxf(s[0],s[1]), fmaxf(s[2],s[3]));
}
__device__ __forceinline__ u32 bminu32(u32 v, u32* s, int tid){
  #pragma unroll
  for (int o = 32; o > 0; o >>= 1){ u32 w = __shfl_down(v, o, 64); v = w < v ? w : v; }
  __syncthreads();
  if ((tid & 63) == 0) s[tid >> 6] = v;
  __syncthreads();
  u32 a = s[0] < s[1] ? s[0] : s[1];
  u32 c = s[2] < s[3] ? s[2] : s[3];
  return a < c ? a : c;
}
__device__ __forceinline__ u64 bminu64(u64 v, u64* s, int tid){
  #pragma unroll
  for (int o = 32; o > 0; o >>= 1){ u64 w = __shfl_down(v, o, 64); v = w < v ? w : v; }
  __syncthreads();
  if ((tid & 63) == 0) s[tid >> 6] = v;
  __syncthreads();
  u64 a = s[0] < s[1] ? s[0] : s[1];
  u64 c = s[2] < s[3] ? s[2] : s[3];
  return a < c ? a : c;
}

__global__ void init_k(double* acc){
  if (threadIdx.x < 8) acc[threadIdx.x] = 0.0;
}

__global__ __launch_bounds__(NT) void main_k(
    const float* __restrict__ osm, const float* __restrict__ agent, const float* __restrict__ vect,
    const float* __restrict__ endp,
    const float* __restrict__ oxw1, const float* __restrict__ oxb1, const float* __restrict__ oxg1, const float* __restrict__ oxbe1,
    const float* __restrict__ oxw2, const float* __restrict__ oxb2,
    const float* __restrict__ tpw1, const float* __restrict__ tpb1, const float* __restrict__ tpg1, const float* __restrict__ tpbe1,
    const float* __restrict__ tpw2, const float* __restrict__ tpb2, const float* __restrict__ tpg2, const float* __restrict__ tpbe2,
    const float* __restrict__ tpw3, const float* __restrict__ tpb3,
    float* __restrict__ out, double* __restrict__ acc)
{
  const int b = blockIdx.x;
  const int tid = threadIdx.x;
  const int lane = tid & 63;
  const int wv = tid >> 6;
  const int lm = lane & 15;
  const int q  = lane >> 4;

  __shared__ u32 keys32[2048];       // mono(dist to origin) per original point
  __shared__ u8  state[2048];
  __shared__ u32 hist[256];
  __shared__ u32 wtot[4];
  __shared__ u32 sc[8];              // 0:Krem 1:pivot 2:done 4:cnt 5:picked-s
  __shared__ u16 sIdx[1024];         // compacted s -> original point idx
  __shared__ float2 ptf2[NS];
  __shared__ float2 tg[NS];
  __shared__ float pol[NS];
  __shared__ float vfs[64], ats[64];
  __shared__ float foxA[64], foxB[64], foxC[64];
  __shared__ float ftpA[64], ftpB[64], ftpC[64];
  __shared__ float w2aS[64], w2bS[64];
  __shared__ float scox[6], sctp[6];
  __shared__ float redf[4];
  __shared__ u32 redu[4];
  __shared__ u64 redk[4];
  __shared__ u16 list50[64];
  __shared__ __align__(16) u16 trans[4][2][16][72];   // per-wave transpose buffers

  const float2* osm2 = (const float2*)osm;
  const float ex = endp[b*2 + 0], ey = endp[b*2 + 1];

  // ---------------- P0: batch vectors, distance keys, state init ----------------
  if (tid < 64){ vfs[tid] = vect[b*64 + tid]; ats[tid] = agent[b*64 + tid]; }
  for (int i = tid; i < NP; i += NT){
    float2 P = osm2[((size_t)b*NP + i)*2];
    keys32[i] = mono(dist_rn(P.x, P.y));
  }
  for (int i = tid; i < 2048; i += NT) state[i] = (i < NP) ? (u8)2 : (u8)0;
  if (tid == 0){ sc[0] = NS; sc[2] = 0; }
  __syncthreads();

  // ---------------- P1: bo/bt partials (feat = [vf, at]) ----------------
  {
    float* part = (float*)&trans[0][0][0][0];   // [8][64]
    int ch = tid & 63, grp = tid >> 6;
    float pox = 0.f, ptp = 0.f;
    for (int k = grp*32; k < grp*32 + 32; ++k){
      float f = (k < 64) ? vfs[k] : ats[k-64];
      pox = fmaf(f, oxw1[k*64 + ch], pox);
      ptp = fmaf(f, tpw1[k*64 + ch], ptp);
    }
    part[grp*64 + ch] = pox;
    part[(grp+4)*64 + ch] = ptp;
    __syncthreads();
    // ---------------- P2: closed-form LN folding (wave 0) ----------------
    if (tid < 64){
      float bo = oxb1[tid] + ((part[0*64+tid]+part[1*64+tid])+(part[2*64+tid]+part[3*64+tid]));
      float bt = tpb1[tid] + ((part[4*64+tid]+part[5*64+tid])+(part[6*64+tid]+part[7*64+tid]));
      float cxo = oxw1[128*64 + tid], cyo = oxw1[129*64 + tid];
      float cxt = tpw1[128*64 + tid], cyt = tpw1[129*64 + tid];
      const float inv64 = 1.0f/64.0f;
      float mb = wred(bo)*inv64, mx_ = wred(cxo)*inv64, my_ = wred(cyo)*inv64;
      float e0 = bo - mb, e1 = cxo - mx_, e2 = cyo - my_;
      float g = oxg1[tid];
      foxA[tid] = e0*g; foxB[tid] = e1*g; foxC[tid] = e2*g;
      float E00 = wred(e0*e0)*inv64, E11 = wred(e1*e1)*inv64, E22 = wred(e2*e2)*inv64;
      float E01 = wred(e0*e1)*inv64, E02 = wred(e0*e2)*inv64, E12 = wred(e1*e2)*inv64;
      if (tid == 0){ scox[0]=E00; scox[1]=E11; scox[2]=E22; scox[3]=E01; scox[4]=E02; scox[5]=E12; }
      float mb2 = wred(bt)*inv64, mx2 = wred(cxt)*inv64, my2 = wred(cyt)*inv64;
      float f0 = bt - mb2, f1 = cxt - mx2, f2 = cyt - my2;
      float gt_ = tpg1[tid];
      ftpA[tid] = f0*gt_; ftpB[tid] = f1*gt_; ftpC[tid] = f2*gt_;
      float F00 = wred(f0*f0)*inv64, F11 = wred(f1*f1)*inv64, F22 = wred(f2*f2)*inv64;
      float F01 = wred(f0*f1)*inv64, F02 = wred(f0*f2)*inv64, F12 = wred(f1*f2)*inv64;
      if (tid == 0){ sctp[0]=F00; sctp[1]=F11; sctp[2]=F22; sctp[3]=F01; sctp[4]=F02; sctp[5]=F12; }
      w2aS[tid] = oxw2[2*tid]; w2bS[tid] = oxw2[2*tid + 1];
    }
  }
  __syncthreads();

  // ---------------- radix select #1: 1000 smallest by (mono(d), idx) ----------------
  {
    const int plist[6] = {7,6,5,4,1,0};
    for (int pi = 0; pi < 6; ++pi){
      if (sc[2]) break;
      const int p = plist[pi];
      hist[tid] = 0; __syncthreads();
      for (int i = tid; i < NP; i += NT) if (state[i] == 2){
        int bb = (p >= 4) ? (int)((keys32[i] >> ((p-4)*8)) & 255) : (int)((((u32)i) >> (p*8)) & 255);
        atomicAdd(&hist[bb], 1u);
      }
      __syncthreads();
      u32 myc = hist[tid], v = myc;
      { int l_ = tid & 63;
        #pragma unroll
        for (int s = 1; s < 64; s <<= 1){ u32 n = __shfl_up(v, s, 64); if (l_ >= s) v += n; }
        if (l_ == 63) wtot[tid >> 6] = v;
      }
      __syncthreads();
      u32 add = 0;
      #pragma unroll
      for (int w = 0; w < 4; ++w) if (w < (tid >> 6)) add += wtot[w];
      u32 myinc = v + add;
      u32 Krem = sc[0];
      bool iamp = false; u32 exc = myinc - myc;
      if (myc > 0 && exc <= Krem-1 && Krem-1 < myinc){ sc[1] = (u32)tid; iamp = true; }
      __syncthreads();
      u32 pb = sc[1];
      for (int i = tid; i < NP; i += NT) if (state[i] == 2){
        int bb = (p >= 4) ? (int)((keys32[i] >> ((p-4)*8)) & 255) : (int)((((u32)i) >> (p*8)) & 255);
        state[i] = (bb < (int)pb) ? (u8)1 : (bb > (int)pb) ? (u8)0 : (u8)2;
      }
      if (iamp){ u32 nk = Krem - exc; sc[0] = nk; if (nk == myc) sc[2] = 1; }
      __syncthreads();
    }
    // compact (selected = state != 0); order arbitrary by design
    if (tid == 0) sc[4] = 0;
    __syncthreads();
    for (int i = tid; i < NP; i += NT) if (state[i] != 0){
      u32 pos = atomicAdd(&sc[4], 1u);
      sIdx[pos] = (u16)i;
      ptf2[pos] = osm2[((size_t)b*NP + i)*2];
    }
    __syncthreads();
  }

  // ---------------- phase-2 per-lane constants ----------------
  const float foxAv = foxA[lane], foxBv = foxB[lane], foxCv = foxC[lane], beoxv = oxbe1[lane];
  const float ftpAv = ftpA[lane], ftpBv = ftpB[lane], ftpCv = ftpC[lane], be2v = tpbe1[lane];
  const float so0 = scox[0], so1 = scox[1], so2 = scox[2], so3 = scox[3], so4 = scox[4], so5 = scox[5];
  const float st0 = sctp[0], st1 = sctp[1], st2 = sctp[2], st3 = sctp[3], st4 = sctp[4], st5 = sctp[5];
  const float oxb20 = oxb2[0], oxb21 = oxb2[1], tpb30 = tpb3[0], tpb31 = tpb3[1];
  float g3c[4], be3c[4], b2i[4], w3a[4], w3b[4];
  #pragma unroll
  for (int nt = 0; nt < 4; ++nt){
    int ch = lm + 16*nt;
    g3c[nt] = tpg2[ch]; be3c[nt] = tpbe2[ch]; b2i[nt] = tpb2[ch];
    w3a[nt] = tpw3[ch*2]; w3b[nt] = tpw3[ch*2 + 1];
  }
  // B fragments of tpw2 (split bf16: Bh + Bl), resident
  short8 bh[2][4], bl[2][4];
  #pragma unroll
  for (int kt = 0; kt < 2; ++kt)
    #pragma unroll
    for (int nt = 0; nt < 4; ++nt){
      short8 H, L;
      #pragma unroll
      for (int j = 0; j < 8; ++j){
        float w = tpw2[(kt*32 + q*8 + j)*64 + nt*16 + lm];
        u16 hh = f2bf(w);
        H[j] = (short)hh;
        L[j] = (short)f2bf(w - bf2f(hh));
      }
      bh[kt][nt] = H; bl[kt][nt] = L;
    }

  // ---------------- phase 2: MLP (per-wave tiles of 16 points) ----------------
  u16* trh  = &trans[wv][0][0][0];
  u16* trl_ = &trans[wv][1][0][0];
  float* trf = (float*)&trans[wv][0][0][0];   // fp32 g1 buffer, stride 68 (overlays both)
  float loff = 0.f;

  for (int t = wv; t < 63; t += 4){
    const int pbase = t*16;
    int sp = pbase + lm; if (sp > NS-1) sp = NS-1;
    const float2 P = ptf2[sp];
    const float px = P.x, py = P.y;
    float var1 = so0 + px*px*so1 + py*py*so2 + 2.0f*(px*so3 + py*so4 + px*py*so5);
    const float r1 = __frsqrt_rn(var1 + 1e-5f);
    // g1 = gelu(LN(ox layer1)) in lane=channel layout -> fp32 transpose buffer
    #pragma unroll
    for (int p = 0; p < 16; ++p){
      float spx = rl(px,p), spy = rl(py,p), sr = rl(r1,p);
      float vv = fmaf(sr, fmaf(spy, foxCv, fmaf(spx, foxBv, foxAv)), beoxv);
      trf[p*68 + lane] = gelu_(vv);
    }
    // offset reduction: lane (lm,q) sums row lm over chs q*16..q*16+15
    f32x4 ga = *(f32x4*)&trf[lm*68 + q*16 + 0];
    f32x4 gb = *(f32x4*)&trf[lm*68 + q*16 + 4];
    f32x4 gc = *(f32x4*)&trf[lm*68 + q*16 + 8];
    f32x4 gd = *(f32x4*)&trf[lm*68 + q*16 + 12];
    f32x4 wa0 = *(f32x4*)&w2aS[q*16+0], wa1 = *(f32x4*)&w2aS[q*16+4], wa2 = *(f32x4*)&w2aS[q*16+8], wa3 = *(f32x4*)&w2aS[q*16+12];
    f32x4 wb0 = *(f32x4*)&w2bS[q*16+0], wb1 = *(f32x4*)&w2bS[q*16+4], wb2 = *(f32x4*)&w2bS[q*16+8], wb3 = *(f32x4*)&w2bS[q*16+12];
    float o0 = 0.f, o1 = 0.f;
    #pragma unroll
    for (int j = 0; j < 4; ++j){
      o0 = fmaf(ga[j],wa0[j], fmaf(gb[j],wa1[j], fmaf(gc[j],wa2[j], fmaf(gd[j],wa3[j], o0))));
      o1 = fmaf(ga[j],wb0[j], fmaf(gb[j],wb1[j], fmaf(gc[j],wb2[j], fmaf(gd[j],wb3[j], o1))));
    }
    o0 += __shfl_xor(o0,16,64); o0 += __shfl_xor(o0,32,64);
    o1 += __shfl_xor(o1,16,64); o1 += __shfl_xor(o1,32,64);
    const float tx = px + o0 + oxb20;
    const float ty = py + o1 + oxb21;
    float var2 = st0 + tx*tx*st1 + ty*ty*st2 + 2.0f*(tx*st3 + ty*st4 + tx*ty*st5);
    const float r2 = __frsqrt_rn(var2 + 1e-5f);
    // g2 = gelu(LN(tp layer1)), split into bf16 hi/lo transpose buffers
    #pragma unroll
    for (int p = 0; p < 16; ++p){
      float stx = rl(tx,p), sty = rl(ty,p), sr = rl(r2,p);
      float vv = fmaf(sr, fmaf(sty, ftpCv, fmaf(stx, ftpBv, ftpAv)), be2v);
      vv = gelu_(vv);
      u16 hh = f2bf(vv);
      trh[p*72 + lane]  = hh;
      trl_[p*72 + lane] = f2bf(vv - bf2f(hh));
    }
    // A-fragments + 3-term split MFMA: h3 = g2 @ tpw2 + b2
    short8 ah0 = *(short8*)&trh[lm*72 + q*8];
    short8 ah1 = *(short8*)&trh[lm*72 + 32 + q*8];
    short8 al0 = *(short8*)&trl_[lm*72 + q*8];
    short8 al1 = *(short8*)&trl_[lm*72 + 32 + q*8];
    f32x4 accv[4];
    #pragma unroll
    for (int nt = 0; nt < 4; ++nt){
      f32x4 c; c[0] = c[1] = c[2] = c[3] = b2i[nt];
      c = __builtin_amdgcn_mfma_f32_16x16x32_bf16(ah0, bh[0][nt], c, 0,0,0);
      c = __builtin_amdgcn_mfma_f32_16x16x32_bf16(ah1, bh[1][nt], c, 0,0,0);
      c = __builtin_amdgcn_mfma_f32_16x16x32_bf16(ah0, bl[0][nt], c, 0,0,0);
      c = __builtin_amdgcn_mfma_f32_16x16x32_bf16(ah1, bl[1][nt], c, 0,0,0);
      c = __builtin_amdgcn_mfma_f32_16x16x32_bf16(al0, bh[0][nt], c, 0,0,0);
      c = __builtin_amdgcn_mfma_f32_16x16x32_bf16(al1, bh[1][nt], c, 0,0,0);
      accv[nt] = c;
    }
    // epilogue in C-layout (row = q*4+e, col = lm + 16*nt): LN3 + gelu + tp3
    float sP[4], qP[4];
    #pragma unroll
    for (int e = 0; e < 4; ++e){
      float a0 = accv[0][e], a1 = accv[1][e], a2 = accv[2][e], a3 = accv[3][e];
      sP[e] = (a0+a1)+(a2+a3);
      qP[e] = fmaf(a0,a0, fmaf(a1,a1, fmaf(a2,a2, a3*a3)));
    }
    #pragma unroll
    for (int s_ = 1; s_ < 16; s_ <<= 1){
      #pragma unroll
      for (int e = 0; e < 4; ++e){ sP[e] += __shfl_xor(sP[e], s_, 64); qP[e] += __shfl_xor(qP[e], s_, 64); }
    }
    float mE[4], rE[4];
    #pragma unroll
    for (int e = 0; e < 4; ++e){
      float m = sP[e] * (1.0f/64.0f);
      float vv = fmaf(sP[e], -m*(1.0f/64.0f), qP[e]*(1.0f/64.0f));
      mE[e] = m; rE[e] = __frsqrt_rn(vv + 1e-5f);
    }
    float uo[4] = {0,0,0,0}, vo[4] = {0,0,0,0};
    #pragma unroll
    for (int nt = 0; nt < 4; ++nt)
      #pragma unroll
      for (int e = 0; e < 4; ++e){
        float g = gelu_(fmaf((accv[nt][e]-mE[e])*rE[e], g3c[nt], be3c[nt]));
        uo[e] = fmaf(g, w3a[nt], uo[e]);
        vo[e] = fmaf(g, w3b[nt], vo[e]);
      }
    #pragma unroll
    for (int s_ = 1; s_ < 16; s_ <<= 1){
      #pragma unroll
      for (int e = 0; e < 4; ++e){ uo[e] += __shfl_xor(uo[e], s_, 64); vo[e] += __shfl_xor(vo[e], s_, 64); }
    }
    if (lm == 0){
      #pragma unroll
      for (int e = 0; e < 4; ++e){
        int pt = pbase + q*4 + e;
        if (pt < NS){
          float t0 = uo[e] + tpb30, t1 = vo[e] + tpb31;
          tg[pt] = make_float2(t0, t1);
          loff += sl1(t0-ex) + sl1(t1-ey);
        }
      }
    }
  }
  __syncthreads();

  // ---------------- phase 3/4: stats, policy, L_cls ----------------
  const float loffT = bsum(loff, redf, tid);
  float sx = 0.f, sy = 0.f;
  for (int s = tid; s < NS; s += NT){ float2 T = tg[s]; sx += T.x; sy += T.y; }
  const float mx = bsum(sx, redf, tid) * (1.0f/NS);
  const float my = bsum(sy, redf, tid) * (1.0f/NS);
  float qx = 0.f, qy = 0.f;
  for (int s = tid; s < NS; s += NT){ float2 T = tg[s]; float dx = T.x-mx, dy = T.y-my; qx = fmaf(dx,dx,qx); qy = fmaf(dy,dy,qy); }
  const float vx = bsum(qx, redf, tid) * (1.0f/(NS-1));
  const float vy = bsum(qy, redf, tid) * (1.0f/(NS-1));
  const float TWO_PI = 6.2831853071795864769f;
  const float rdx = __frcp_rn(__fsqrt_rn(TWO_PI*vx + 1e-6f));
  const float rdy = __frcp_rn(__fsqrt_rn(TWO_PI*vy + 1e-6f));
  float pmaxl = -1e30f;
  for (int s = tid; s < NS; s += NT){
    float2 T = tg[s]; float dx = T.x-mx, dy = T.y-my;
    float pdx = expf(-0.5f*dx*dx/vx + 1e-6f) * rdx;
    float pdy = expf(-0.5f*dy*dy/vy + 1e-6f) * rdy;
    float pp = pdx*pdy;
    pol[s] = pp;
    pmaxl = fmaxf(pmaxl, pp);
  }
  const float pmax = bmax(pmaxl, redf, tid);
  float se = 0.f;
  for (int s = tid; s < NS; s += NT) se += expf(pol[s] - pmax);
  const float sume = bsum(se, redf, tid);

  // target_index: exact argmax of -d/T with rank tie-break (3 scans)
  u32 xkm = 0xFFFFFFFFu;
  for (int s = tid; s < NS; s += NT){
    float2 Pp = ptf2[s];
    float dd = dist_rn(Pp.x-ex, Pp.y-ey);
    u32 xk = ~mono((0.0f - dd) / 0.01f);
    if (xk < xkm) xkm = xk;
  }
  xkm = bminu32(xkm, redu, tid);
  u64 dmin = 0xFFFFFFFFFFFFFFFFull;
  for (int s = tid; s < NS; s += NT){
    float2 Pp = ptf2[s];
    float dd = dist_rn(Pp.x-ex, Pp.y-ey);
    u32 xk = ~mono((0.0f - dd) / 0.01f);
    if (xk == xkm){ u32 oi = sIdx[s]; u64 dk = (((u64)keys32[oi]) << 32) | (u64)oi; if (dk < dmin) dmin = dk; }
  }
  dmin = bminu64(dmin, redk, tid);
  for (int s = tid; s < NS; s += NT){
    float2 Pp = ptf2[s];
    float dd = dist_rn(Pp.x-ex, Pp.y-ey);
    u32 xk = ~mono((0.0f - dd) / 0.01f);
    u32 oi = sIdx[s];
    if (xk == xkm && ((((u64)keys32[oi]) << 32) | (u64)oi) == dmin) sc[5] = (u32)s;
  }
  __syncthreads();
  if (tid == 0){
    float lse = pmax + logf(sume);
    float picked = pol[sc[5]];
    atomicAdd(&acc[0], (double)(lse - picked));
    atomicAdd(&acc[1], (double)loffT);
  }

  // ---------------- radix select #2: top-50 by (~mono(pol), mono(d), idx) ----------------
  for (int i = tid; i < 2048; i += NT) state[i] = (i < NS) ? (u8)2 : (u8)0;
  if (tid == 0){ sc[0] = NO; sc[2] = 0; }
  __syncthreads();
  {
    const int plist2[10] = {11,10,9,8,7,6,5,4,1,0};
    for (int pi = 0; pi < 10; ++pi){
      if (sc[2]) break;
      const int p = plist2[pi];
      hist[tid] = 0; __syncthreads();
      for (int i = tid; i < NS; i += NT) if (state[i] == 2){
        u32 oi = sIdx[i];
        int bb = (p >= 8) ? (int)(((~mono(pol[i])) >> ((p-8)*8)) & 255)
               : (p >= 4) ? (int)((keys32[oi] >> ((p-4)*8)) & 255)
               : (int)((((u32)oi) >> (p*8)) & 255);
        atomicAdd(&hist[bb], 1u);
      }
      __syncthreads();
      u32 myc = hist[tid], v = myc;
      { int l_ = tid & 63;
        #pragma unroll
        for (int s = 1; s < 64; s <<= 1){ u32 n = __shfl_up(v, s, 64); if (l_ >= s) v += n; }
        if (l_ == 63) wtot[tid >> 6] = v;
      }
      __syncthreads();
      u32 add = 0;
      #pragma unroll
      for (int w = 0; w < 4; ++w) if (w < (tid >> 6)) add += wtot[w];
      u32 myinc = v + add;
      u32 Krem = sc[0];
      bool iamp = false; u32 exc = myinc - myc;
      if (myc > 0 && exc <= Krem-1 && Krem-1 < myinc){ sc[1] = (u32)tid; iamp = true; }
      __syncthreads();
      u32 pb = sc[1];
      for (int i = tid; i < NS; i += NT) if (state[i] == 2){
        u32 oi = sIdx[i];
        int bb = (p >= 8) ? (int)(((~mono(pol[i])) >> ((p-8)*8)) & 255)
               : (p >= 4) ? (int)((keys32[oi] >> ((p-4)*8)) & 255)
               : (int)((((u32)oi) >> (p*8)) & 255);
        state[i] = (bb < (int)pb) ? (u8)1 : (bb > (int)pb) ? (u8)0 : (u8)2;
      }
      if (iamp){ u32 nk = Krem - exc; sc[0] = nk; if (nk == myc) sc[2] = 1; }
      __syncthreads();
    }
  }
  if (tid == 0) sc[4] = 0;
  __syncthreads();
  for (int i = tid; i < NS; i += NT) if (state[i] != 0){
    u32 pos = atomicAdd(&sc[4], 1u);
    list50[pos] = (u16)i;
  }
  __syncthreads();

  // ---------------- phase 5: single-wave bitonic-64 sort of the 50, write, L_end ----------------
  if (wv == 0){
    u64 hi; u32 lo; int s;
    if (lane < NO){
      s = (int)list50[lane];
      u32 oi = sIdx[s];
      hi = (((u64)(~mono(pol[s]))) << 32) | (u64)keys32[oi];
      lo = oi;
    } else { hi = 0xFFFFFFFFFFFFFFFFull; lo = 0xFFFFFFFFu; s = 0; }
    #pragma unroll
    for (int k = 2; k <= 64; k <<= 1){
      #pragma unroll
      for (int j = k >> 1; j > 0; j >>= 1){
        u64 ohi = __shfl_xor(hi, j, 64);
        u32 olo = __shfl_xor(lo, j, 64);
        int os  = __shfl_xor(s,  j, 64);
        bool up = ((lane & k) == 0);
        bool lower = ((lane & j) == 0);
        bool gt = (hi > ohi) || ((hi == ohi) && (lo > olo));
        bool lt = (hi < ohi) || ((hi == ohi) && (lo < olo));
        bool take = (up == lower) ? gt : lt;
        if (take){ hi = ohi; lo = olo; s = os; }
      }
    }
    float le = 0.f;
    if (lane < NO){
      float2 T = tg[s];
      out[2 + ((size_t)b*NO + lane)*2 + 0] = T.x;
      out[2 + ((size_t)b*NO + lane)*2 + 1] = T.y;
      le = sl1(T.x-ex) + sl1(T.y-ey);
    }
    #pragma unroll
    for (int o = 32; o > 0; o >>= 1) le += __shfl_down(le, o, 64);
    if (lane == 0) atomicAdd(&acc[2], (double)le);
  }
}

__global__ void fin_k(const double* acc, float* out){
  if (threadIdx.x == 0){
    out[0] = (float)(acc[0] / (double)NB);
    out[1] = (float)(acc[1] / ((double)NB*NS*2) + 3.0 * (acc[2] / ((double)NB*NO*2)));
  }
}

extern "C" void kernel_launch(void* const* d_in, const int* in_sizes, int n_in,
                              void* d_out, int out_size, void* d_ws, size_t ws_size,
                              hipStream_t stream){
  const float* osm   = (const float*)d_in[0];
  const float* agent = (const float*)d_in[1];
  const float* vect  = (const float*)d_in[2];
  const float* endp  = (const float*)d_in[3];
  // d_in[4] = speed (unused)
  const float* oxw1  = (const float*)d_in[5];
  const float* oxb1  = (const float*)d_in[6];
  const float* oxg1  = (const float*)d_in[7];
  const float* oxbe1 = (const float*)d_in[8];
  const float* oxw2  = (const float*)d_in[9];
  const float* oxb2  = (const float*)d_in[10];
  const float* tpw1  = (const float*)d_in[11];
  const float* tpb1  = (const float*)d_in[12];
  const float* tpg1  = (const float*)d_in[13];
  const float* tpbe1 = (const float*)d_in[14];
  const float* tpw2  = (const float*)d_in[15];
  const float* tpb2  = (const float*)d_in[16];
  const float* tpg2  = (const float*)d_in[17];
  const float* tpbe2 = (const float*)d_in[18];
  const float* tpw3  = (const float*)d_in[19];
  const float* tpb3  = (const float*)d_in[20];
  float* out = (float*)d_out;
  double* acc = (double*)d_ws;

  hipLaunchKernelGGL(init_k, dim3(1), dim3(64), 0, stream, acc);
  hipLaunchKernelGGL(main_k, dim3(NB), dim3(NT), 0, stream,
    osm, agent, vect, endp,
    oxw1, oxb1, oxg1, oxbe1, oxw2, oxb2,
    tpw1, tpb1, tpg1, tpbe1, tpw2, tpb2, tpg2, tpbe2, tpw3, tpb3,
    out, acc);
  hipLaunchKernelGGL(fin_k, dim3(1), dim3(64), 0, stream, acc, out);
}